// Round 11
// baseline (207.245 us; speedup 1.0000x reference)
//
#include <hip/hip_runtime.h>
#include <hip/hip_bf16.h>
#include <stdint.h>

#define AS1 __attribute__((address_space(1)))
#define AS3 __attribute__((address_space(3)))

typedef __bf16 bf16x8 __attribute__((ext_vector_type(8)));
typedef float f32x4 __attribute__((ext_vector_type(4)));

__device__ __forceinline__ float fast_tanh(float x) {
    float e = __expf(2.0f * x);           // inf/0 endpoints give +/-1 exactly, no NaN
    return 1.0f - 2.0f / (e + 1.0f);
}

__device__ __forceinline__ float ldin(const void* p, int idx, int f32) {
    return f32 ? ((const float*)p)[idx]
               : __bfloat162float(((const __hip_bfloat16*)p)[idx]);
}

__device__ __forceinline__ unsigned short f2bf(float v) {
    __hip_bfloat16 h = __float2bfloat16(v);
    return *(unsigned short*)&h;
}

// NOTE (R9 lesson): the `offset` immediate of this builtin is NOT a plain
// global-address offset on gfx950 — nonzero values corrupt the transfer.
// Always pass 0 and advance the pointer.
__device__ __forceinline__ void gload_lds16(const __hip_bfloat16* g, AS3 char* l) {
    __builtin_amdgcn_global_load_lds((AS1 void*)g, (AS3 void*)l, 16, 0, 0);
}

// ---------------------------------------------------------------------------
// 64x64 weight-transpose tile (coalesced both sides via LDS, +1-pad fp32).
// WcT[n][k] = n<dout ? [Wr | -Wi] : [Wi | Wr]  (cols: k<din | k>=din).
// smem must hold 64*65*4 = 16640 B.
// ---------------------------------------------------------------------------
__device__ __forceinline__ void wt_tile(const void* Wr, const void* Wi,
                                        int din, int dout_, int KT, int nt, int kt,
                                        __hip_bfloat16* dst, int f32, char* smem)
{
    float (*T)[65] = (float(*)[65])smem;
    const int t = threadIdx.x;
    const int n0 = nt * 64, k0 = kt * 64;
    const void* src; float sg; int col0, krel;
    if (n0 < dout_) {
        col0 = n0;
        if (k0 < din) { src = Wr; sg =  1.f; krel = k0; }
        else          { src = Wi; sg = -1.f; krel = k0 - din; }
    } else {
        col0 = n0 - dout_;
        if (k0 < din) { src = Wi; sg =  1.f; krel = k0; }
        else          { src = Wr; sg =  1.f; krel = k0 - din; }
    }
    const int lr = t >> 4, lc = t & 15;
#pragma unroll
    for (int p = 0; p < 4; ++p) {
        const int r = p * 16 + lr;
        const int c = lc * 4;
        const size_t gi = (size_t)(krel + r) * dout_ + col0 + c;
        float v0, v1, v2, v3;
        if (f32) {
            float4 v = *(const float4*)((const float*)src + gi);
            v0 = v.x; v1 = v.y; v2 = v.z; v3 = v.w;
        } else {
            ushort4 u = *(const ushort4*)((const unsigned short*)src + gi);
            __hip_bfloat16 h0, h1, h2, h3;
            *(unsigned short*)&h0 = u.x; *(unsigned short*)&h1 = u.y;
            *(unsigned short*)&h2 = u.z; *(unsigned short*)&h3 = u.w;
            v0 = __bfloat162float(h0); v1 = __bfloat162float(h1);
            v2 = __bfloat162float(h2); v3 = __bfloat162float(h3);
        }
        T[r][c] = sg * v0; T[r][c + 1] = sg * v1;
        T[r][c + 2] = sg * v2; T[r][c + 3] = sg * v3;
    }
    __syncthreads();
#pragma unroll
    for (int q = 0; q < 4; ++q) {
        const int n = q * 16 + lr;
        const int k8 = lc;
        ushort4 u;
        u.x = f2bf(T[k8 * 4 + 0][n]); u.y = f2bf(T[k8 * 4 + 1][n]);
        u.z = f2bf(T[k8 * 4 + 2][n]); u.w = f2bf(T[k8 * 4 + 3][n]);
        *(ushort4*)((unsigned short*)dst + (size_t)(n0 + n) * KT + k0 + k8 * 4) = u;
    }
}

// ---------------------------------------------------------------------------
// Setup1: 653 blocks. [0,128) hopf | [128,640) WT0 transpose | [640,653) bias
// (block 640 publishes the dtype flag). Per-block inline dtype probe on z's
// first 512 u16 words (fp32 data ~22% huge bf16 exponents; bf16 none).
// ---------------------------------------------------------------------------
__global__ __launch_bounds__(256)
void setup1(const void* __restrict__ z, const void* __restrict__ omega,
            const void* __restrict__ bc,
            const void* __restrict__ W0r, const void* __restrict__ W0i,
            const void* __restrict__ b0r, const void* __restrict__ b0i,
            const void* __restrict__ b1r, const void* __restrict__ b1i,
            const void* __restrict__ b2r,
            __hip_bfloat16* __restrict__ Z, __hip_bfloat16* __restrict__ WT0,
            float* __restrict__ biasOut, int* __restrict__ flagOut,
            char* __restrict__ dout)
{
    __shared__ __align__(16) char smem[16640];
    __shared__ int sflag;
    const int t   = threadIdx.x;
    const int bid = blockIdx.x;

    if (t == 0) sflag = 0;
    __syncthreads();
    {
        const unsigned short* zz = (const unsigned short*)z;
        const int c = ((((zz[t] >> 7) & 0xFF) >= 0xC8) ? 1 : 0)
                    + ((((zz[t + 256] >> 7) & 0xFF) >= 0xC8) ? 1 : 0);
        if (c) atomicAdd(&sflag, c);
    }
    __syncthreads();
    const int f32 = (sflag > 8) ? 1 : 0;

    if (bid < 128) {
        // Hopf trajectory: one thread per (b,i), 128 fp32 Euler steps
        const int tid = bid * 256 + t;
        const int b = tid >> 9;
        const int i = tid & 511;
        float x = ldin(z, b * 1024 + i, f32);
        float y = ldin(z, b * 1024 + 512 + i, f32);
        const float om = ldin(omega, b, f32);
        const float bb = ldin(bc, b * 512 + i, f32);
        const float w  = om * (float)(i + 1);
        __hip_bfloat16* zt = Z + b * 1024 + i;
        for (int s = 0; s < 128; ++s) {
            const float r2 = x * x + y * y;
            const float f  = bb - r2;
            const float dx = f * x - w * y;
            const float dy = f * y + w * x;
            x += 0.001f * dx;
            y += 0.001f * dy;
            zt[s * 65536]       = __float2bfloat16(x);
            zt[s * 65536 + 512] = __float2bfloat16(y);
            if (s == 0) {
                if (f32) {
                    float* o = (float*)(dout + (size_t)2097152 * 4);
                    o[b * 1024 + i] = x; o[b * 1024 + 512 + i] = y;
                } else {
                    __hip_bfloat16* o = (__hip_bfloat16*)(dout + (size_t)2097152 * 2);
                    o[b * 1024 + i] = __float2bfloat16(x);
                    o[b * 1024 + 512 + i] = __float2bfloat16(y);
                }
            }
        }
        return;
    }

    if (bid >= 640) {
        if (bid == 640 && t == 0) *flagOut = f32;
        const int idx = (bid - 640) * 256 + t;   // [0,3328)
        float v;
        if      (idx < 1024) v = ldin(b0r, idx, f32);
        else if (idx < 2048) v = ldin(b0i, idx - 1024, f32);
        else if (idx < 2560) v = ldin(b1r, idx - 2048, f32);
        else if (idx < 3072) v = ldin(b1i, idx - 2560, f32);
        else                 v = ldin(b2r, idx - 3072, f32);
        biasOut[idx] = v;
        return;
    }

    // WT0: 2048 x 1024, tiles: nt = u>>4 (32), kt = u&15 (16)
    const int u = bid - 128;
    wt_tile(W0r, W0i, 512, 1024, 1024, u >> 4, u & 15, WT0, f32, smem);
}

// ---------------------------------------------------------------------------
// Double-buffered GEMM core: C = tanh(A @ Bt^T + bias). MT x NT tile, BK=64,
// 4 waves (2x2), 16x16x32 bf16 MFMA, XOR-swizzled LDS (slot = q ^ (row&7);
// 0 conflicts, R3). Dbuf: stage(kt+1 -> other half) | compute(kt) | barrier
// (vmcnt(0) drain lands after the ~900-cyc MFMA window -> latency hidden).
//
// XCD mapping (R11): partition **M** across XCDs, n fastest within an XCD:
//   xcd = bid&7, r = bid>>3, mt = xcd*MS + r/GX, nt = r%GX.
// Each XCD re-reads only its A-slice (2-4 MB, fits its private 4MB L2); B is
// shared by all XCDs and stays L3-resident. (Old N-partition made every XCD
// stream the whole A: G1 FETCH 135MB vs 36MB compulsory.)
// Grid must be 8*MS*GX. MODE 1: scatter r=t*64+b -> out[b][t][c], per f32.
// ---------------------------------------------------------------------------
template<int MT, int NT, int GX, int MS, int MODE>
__device__ __forceinline__ void gemm_core(int bid,
                                          const __hip_bfloat16* __restrict__ A,
                                          const __hip_bfloat16* __restrict__ Bt,
                                          const float* __restrict__ bias,
                                          void* __restrict__ Cv, int f32,
                                          int N, int K, char* smem)
{
    constexpr int AI = MT / 32;
    constexpr int BJ = NT / 32;
    constexpr int HALF = (MT + NT) * 128;

    const int tid = threadIdx.x, lane = tid & 63, w = tid >> 6;
    const int wx = w & 1, wy = w >> 1;

    const int xcd = bid & 7, r = bid >> 3;
    const int mt = xcd * MS + r / GX;
    const int nt = r % GX;
    const int m0 = mt * MT;
    const int n0 = nt * NT;

    // staging: 16B chunk at (row, slot s) holds global k-quad q = s ^ (row&7)
    const int sl = lane & 7, lr8 = lane >> 3;
    const __hip_bfloat16* gA[AI];
    const __hip_bfloat16* gB[BJ];
#pragma unroll
    for (int p = 0; p < AI; ++p) {
        const int row = w * (MT / 4) + p * 8 + lr8;
        gA[p] = A + (size_t)(m0 + row) * K + (sl ^ (row & 7)) * 8;
    }
#pragma unroll
    for (int p = 0; p < BJ; ++p) {
        const int row = w * (NT / 4) + p * 8 + lr8;
        gB[p] = Bt + (size_t)(n0 + row) * K + (sl ^ (row & 7)) * 8;
    }
    AS3 char* lA0 = (AS3 char*)smem + w * (MT * 32);
    AS3 char* lB0 = (AS3 char*)smem + MT * 128 + w * (NT * 32);

    // fragment reads: row R, k-quad KQ = ks*4+fq, slot = KQ ^ (R&7)
    const int fr = lane & 15, fq = lane >> 4;
    const int swz = (fq ^ (fr & 7)) * 8;
    const int arow = wy * (MT / 2) + fr;
    const int brow = wx * (NT / 2) + fr;

    f32x4 acc[AI][BJ];
#pragma unroll
    for (int i = 0; i < AI; ++i)
#pragma unroll
        for (int j = 0; j < BJ; ++j)
            acc[i][j] = (f32x4){0.f, 0.f, 0.f, 0.f};

    // prologue: stage kt=0 into half 0
#pragma unroll
    for (int p = 0; p < AI; ++p) gload_lds16(gA[p], lA0 + p * 1024);
#pragma unroll
    for (int p = 0; p < BJ; ++p) gload_lds16(gB[p], lB0 + p * 1024);
    __syncthreads();

    const int NKT = K >> 6;
    for (int kt = 0; kt < NKT; ++kt) {
        const int cur = (kt & 1) ? HALF : 0;
        // prefetch kt+1 into the other half (overwrites data last read at kt-1,
        // which every wave finished before the barrier that ended iter kt-1)
        if (kt + 1 < NKT) {
            const int nxt = cur ^ HALF;
            const int kk = (kt + 1) << 6;
#pragma unroll
            for (int p = 0; p < AI; ++p) gload_lds16(gA[p] + kk, lA0 + nxt + p * 1024);
#pragma unroll
            for (int p = 0; p < BJ; ++p) gload_lds16(gB[p] + kk, lB0 + nxt + p * 1024);
        }
        const __hip_bfloat16* As = (const __hip_bfloat16*)(smem + cur);
        const __hip_bfloat16* Bs = (const __hip_bfloat16*)(smem + cur + MT * 128);
#pragma unroll
        for (int ks = 0; ks < 2; ++ks) {
            const int so = swz ^ (ks << 5);
            bf16x8 af[AI], bv[BJ];
#pragma unroll
            for (int i = 0; i < AI; ++i)
                af[i] = *(const bf16x8*)(As + (arow + i * 16) * 64 + so);
#pragma unroll
            for (int j = 0; j < BJ; ++j)
                bv[j] = *(const bf16x8*)(Bs + (brow + j * 16) * 64 + so);
#pragma unroll
            for (int i = 0; i < AI; ++i)
#pragma unroll
                for (int j = 0; j < BJ; ++j)
                    acc[i][j] = __builtin_amdgcn_mfma_f32_16x16x32_bf16(af[i], bv[j], acc[i][j], 0, 0, 0);
        }
        __syncthreads();   // drains the kt+1 prefetch AFTER the compute window
    }

    // epilogue: C/D layout col = lane&15, row = (lane>>4)*4 + reg
    const int col_l = lane & 15;
    const int rq    = lane >> 4;
    float bvv[BJ];
#pragma unroll
    for (int j = 0; j < BJ; ++j)
        bvv[j] = bias[n0 + wx * (NT / 2) + j * 16 + col_l];

#pragma unroll
    for (int i = 0; i < AI; ++i) {
#pragma unroll
        for (int j = 0; j < BJ; ++j) {
            const int gc = n0 + wx * (NT / 2) + j * 16 + col_l;
#pragma unroll
            for (int r2 = 0; r2 < 4; ++r2) {
                const int gr = m0 + wy * (MT / 2) + i * 16 + rq * 4 + r2;
                const float v = fast_tanh(acc[i][j][r2] + bvv[j]);
                if (MODE == 0) {
                    ((__hip_bfloat16*)Cv)[(size_t)gr * (size_t)N + gc] = __float2bfloat16(v);
                } else {
                    const size_t idx = (size_t)(gr & 63) * 32768 + (size_t)(gr >> 6) * 256 + (size_t)gc;
                    if (f32) ((float*)Cv)[idx] = v;
                    else     ((__hip_bfloat16*)Cv)[idx] = __float2bfloat16(v);
                }
            }
        }
    }
}

// ---------------------------------------------------------------------------
// D2: blocks [0,2048) = G0 tiles (64x128 dbuf, M-partitioned XCD map);
// [2048,2560) = WT1 transpose; [2560,2624) = WT2 transpose (tail slack).
// ---------------------------------------------------------------------------
__global__ __launch_bounds__(256)
void gemm0_wt(const __hip_bfloat16* __restrict__ A,
              const __hip_bfloat16* __restrict__ Bt,
              const float* __restrict__ bias, void* __restrict__ Cv,
              const void* __restrict__ W1r, const void* __restrict__ W1i,
              const void* __restrict__ W2r, const void* __restrict__ W2i,
              __hip_bfloat16* __restrict__ WT1, __hip_bfloat16* __restrict__ WT2,
              const int* __restrict__ flag)
{
    __shared__ __align__(16) char smem[49152];   // 2 x (64+128)*128
    const int bid = blockIdx.x;
    if (bid < 2048) {
        // G0: 128 m-tiles (MS=16/XCD), 16 n-tiles
        gemm_core<64, 128, 16, 16, 0>(bid, A, Bt, bias, Cv, 0, 2048, 1024, smem);
    } else if (bid < 2560) {
        const int u = bid - 2048;   // WT1: 1024 x 2048, nt = u>>5 (16), kt = u&31 (32)
        wt_tile(W1r, W1i, 1024, 512, 2048, u >> 5, u & 31, WT1, *flag, smem);
    } else {
        const int u = bid - 2560;   // WT2: 256 x 1024, nt = u>>4 (4), kt = u&15 (16)
        wt_tile(W2r, W2i, 512, 256, 1024, u >> 4, u & 15, WT2, *flag, smem);
    }
}

template<int MT, int NT, int GX, int MS, int MODE>
__global__ __launch_bounds__(256)
void gemm_k(const __hip_bfloat16* __restrict__ A, const __hip_bfloat16* __restrict__ Bt,
            const float* __restrict__ bias, void* __restrict__ Cv,
            const int* __restrict__ flag, int N, int K)
{
    __shared__ __align__(16) char smem[2 * (MT + NT) * 128];
    const int f32 = (MODE == 1) ? *flag : 0;
    gemm_core<MT, NT, GX, MS, MODE>(blockIdx.x, A, Bt, bias, Cv, f32, N, K, smem);
}

// ---------------------------------------------------------------------------
// ws: [0,16M) Z (8192x1024 bf16; reused as H1), [16M,48M) H0 (8192x2048),
// [48M) WT0 4M, [52M) WT1 4M, [56M) WT2 0.5M, [56M+512K) bias f32, [57M) flag.
// ---------------------------------------------------------------------------
extern "C" void kernel_launch(void* const* d_in, const int* in_sizes, int n_in,
                              void* d_out, int out_size, void* d_ws, size_t ws_size,
                              hipStream_t stream)
{
    (void)in_sizes; (void)n_in; (void)out_size; (void)ws_size;
    char* ws = (char*)d_ws;
    __hip_bfloat16* Z    = (__hip_bfloat16*)(ws);
    __hip_bfloat16* H0   = (__hip_bfloat16*)(ws + (16u << 20));
    __hip_bfloat16* WT0  = (__hip_bfloat16*)(ws + (48u << 20));
    __hip_bfloat16* WT1  = (__hip_bfloat16*)(ws + (52u << 20));
    __hip_bfloat16* WT2  = (__hip_bfloat16*)(ws + (56u << 20));
    float*          bias = (float*)        (ws + (56u << 20) + (512u << 10));
    int*            flag = (int*)          (ws + (57u << 20));

    // D1: hopf + WT0 + bias (+flag publish)
    setup1<<<653, 256, 0, stream>>>(d_in[0], d_in[1], d_in[2], d_in[3], d_in[4],
                                    d_in[5], d_in[6], d_in[9], d_in[10], d_in[13],
                                    Z, WT0, bias, flag, (char*)d_out);

    // D2: G0 (Z @ WT0^T -> H0, 8192x2048), 64x128 dbuf, M-partitioned XCD map
    //     + WT1/WT2 transposes in tail slack
    gemm0_wt<<<2624, 256, 0, stream>>>(Z, WT0, bias, H0,
                                       d_in[7], d_in[8], d_in[11], d_in[12],
                                       WT1, WT2, flag);

    // D3: G1 = H0 @ WT1^T -> H1=Z (8192x1024). 64x128 dbuf, 1024 blocks (MS=16, GX=8).
    gemm_k<64, 128, 8, 16, 0><<<1024, 256, 0, stream>>>(H0, WT1, bias + 2048, Z, flag, 1024, 2048);

    // D4: G2 = H1 @ WT2^T -> out[b][t][c] (N=256). 64x64 dbuf, 512 blocks (MS=16, GX=4).
    gemm_k<64, 64, 4, 16, 1><<<512, 256, 0, stream>>>(Z, WT2, bias + 3072, d_out, flag, 256, 1024);
}

// Round 12
// 192.060 us; speedup vs baseline: 1.0791x; 1.0791x over previous
//
#include <hip/hip_runtime.h>
#include <hip/hip_bf16.h>
#include <stdint.h>

#define AS1 __attribute__((address_space(1)))
#define AS3 __attribute__((address_space(3)))

typedef __bf16 bf16x8 __attribute__((ext_vector_type(8)));
typedef float f32x4 __attribute__((ext_vector_type(4)));

__device__ __forceinline__ float fast_tanh(float x) {
    float e = __expf(2.0f * x);           // inf/0 endpoints give +/-1 exactly, no NaN
    return 1.0f - 2.0f / (e + 1.0f);
}

__device__ __forceinline__ float ldin(const void* p, int idx, int f32) {
    return f32 ? ((const float*)p)[idx]
               : __bfloat162float(((const __hip_bfloat16*)p)[idx]);
}

__device__ __forceinline__ unsigned short f2bf(float v) {
    __hip_bfloat16 h = __float2bfloat16(v);
    return *(unsigned short*)&h;
}

// NOTE (R9 lesson): the `offset` immediate of this builtin is NOT a plain
// global-address offset on gfx950 — nonzero values corrupt the transfer.
// Always pass 0 and advance the pointer.
__device__ __forceinline__ void gload_lds16(const __hip_bfloat16* g, AS3 char* l) {
    __builtin_amdgcn_global_load_lds((AS1 void*)g, (AS3 void*)l, 16, 0, 0);
}

// ---------------------------------------------------------------------------
// 64x64 weight-transpose tile (coalesced both sides via LDS, +1-pad fp32).
// WcT[n][k] = n<dout ? [Wr | -Wi] : [Wi | Wr]  (cols: k<din | k>=din).
// smem must hold 64*65*4 = 16640 B.
// ---------------------------------------------------------------------------
__device__ __forceinline__ void wt_tile(const void* Wr, const void* Wi,
                                        int din, int dout_, int KT, int nt, int kt,
                                        __hip_bfloat16* dst, int f32, char* smem)
{
    float (*T)[65] = (float(*)[65])smem;
    const int t = threadIdx.x;
    const int n0 = nt * 64, k0 = kt * 64;
    const void* src; float sg; int col0, krel;
    if (n0 < dout_) {
        col0 = n0;
        if (k0 < din) { src = Wr; sg =  1.f; krel = k0; }
        else          { src = Wi; sg = -1.f; krel = k0 - din; }
    } else {
        col0 = n0 - dout_;
        if (k0 < din) { src = Wi; sg =  1.f; krel = k0; }
        else          { src = Wr; sg =  1.f; krel = k0 - din; }
    }
    const int lr = t >> 4, lc = t & 15;
#pragma unroll
    for (int p = 0; p < 4; ++p) {
        const int r = p * 16 + lr;
        const int c = lc * 4;
        const size_t gi = (size_t)(krel + r) * dout_ + col0 + c;
        float v0, v1, v2, v3;
        if (f32) {
            float4 v = *(const float4*)((const float*)src + gi);
            v0 = v.x; v1 = v.y; v2 = v.z; v3 = v.w;
        } else {
            ushort4 u = *(const ushort4*)((const unsigned short*)src + gi);
            __hip_bfloat16 h0, h1, h2, h3;
            *(unsigned short*)&h0 = u.x; *(unsigned short*)&h1 = u.y;
            *(unsigned short*)&h2 = u.z; *(unsigned short*)&h3 = u.w;
            v0 = __bfloat162float(h0); v1 = __bfloat162float(h1);
            v2 = __bfloat162float(h2); v3 = __bfloat162float(h3);
        }
        T[r][c] = sg * v0; T[r][c + 1] = sg * v1;
        T[r][c + 2] = sg * v2; T[r][c + 3] = sg * v3;
    }
    __syncthreads();
#pragma unroll
    for (int q = 0; q < 4; ++q) {
        const int n = q * 16 + lr;
        const int k8 = lc;
        ushort4 u;
        u.x = f2bf(T[k8 * 4 + 0][n]); u.y = f2bf(T[k8 * 4 + 1][n]);
        u.z = f2bf(T[k8 * 4 + 2][n]); u.w = f2bf(T[k8 * 4 + 3][n]);
        *(ushort4*)((unsigned short*)dst + (size_t)(n0 + n) * KT + k0 + k8 * 4) = u;
    }
}

// ---------------------------------------------------------------------------
// Setup1: 653 blocks. [0,128) hopf | [128,640) WT0 transpose | [640,653) bias
// (block 640 publishes the dtype flag). Per-block inline dtype probe on z's
// first 512 u16 words (fp32 data ~22% huge bf16 exponents; bf16 none).
// ---------------------------------------------------------------------------
__global__ __launch_bounds__(256)
void setup1(const void* __restrict__ z, const void* __restrict__ omega,
            const void* __restrict__ bc,
            const void* __restrict__ W0r, const void* __restrict__ W0i,
            const void* __restrict__ b0r, const void* __restrict__ b0i,
            const void* __restrict__ b1r, const void* __restrict__ b1i,
            const void* __restrict__ b2r,
            __hip_bfloat16* __restrict__ Z, __hip_bfloat16* __restrict__ WT0,
            float* __restrict__ biasOut, int* __restrict__ flagOut,
            char* __restrict__ dout)
{
    __shared__ __align__(16) char smem[16640];
    __shared__ int sflag;
    const int t   = threadIdx.x;
    const int bid = blockIdx.x;

    if (t == 0) sflag = 0;
    __syncthreads();
    {
        const unsigned short* zz = (const unsigned short*)z;
        const int c = ((((zz[t] >> 7) & 0xFF) >= 0xC8) ? 1 : 0)
                    + ((((zz[t + 256] >> 7) & 0xFF) >= 0xC8) ? 1 : 0);
        if (c) atomicAdd(&sflag, c);
    }
    __syncthreads();
    const int f32 = (sflag > 8) ? 1 : 0;

    if (bid < 128) {
        // Hopf trajectory: one thread per (b,i), 128 fp32 Euler steps
        const int tid = bid * 256 + t;
        const int b = tid >> 9;
        const int i = tid & 511;
        float x = ldin(z, b * 1024 + i, f32);
        float y = ldin(z, b * 1024 + 512 + i, f32);
        const float om = ldin(omega, b, f32);
        const float bb = ldin(bc, b * 512 + i, f32);
        const float w  = om * (float)(i + 1);
        __hip_bfloat16* zt = Z + b * 1024 + i;
        for (int s = 0; s < 128; ++s) {
            const float r2 = x * x + y * y;
            const float f  = bb - r2;
            const float dx = f * x - w * y;
            const float dy = f * y + w * x;
            x += 0.001f * dx;
            y += 0.001f * dy;
            zt[s * 65536]       = __float2bfloat16(x);
            zt[s * 65536 + 512] = __float2bfloat16(y);
            if (s == 0) {
                if (f32) {
                    float* o = (float*)(dout + (size_t)2097152 * 4);
                    o[b * 1024 + i] = x; o[b * 1024 + 512 + i] = y;
                } else {
                    __hip_bfloat16* o = (__hip_bfloat16*)(dout + (size_t)2097152 * 2);
                    o[b * 1024 + i] = __float2bfloat16(x);
                    o[b * 1024 + 512 + i] = __float2bfloat16(y);
                }
            }
        }
        return;
    }

    if (bid >= 640) {
        if (bid == 640 && t == 0) *flagOut = f32;
        const int idx = (bid - 640) * 256 + t;   // [0,3328)
        float v;
        if      (idx < 1024) v = ldin(b0r, idx, f32);
        else if (idx < 2048) v = ldin(b0i, idx - 1024, f32);
        else if (idx < 2560) v = ldin(b1r, idx - 2048, f32);
        else if (idx < 3072) v = ldin(b1i, idx - 2560, f32);
        else                 v = ldin(b2r, idx - 3072, f32);
        biasOut[idx] = v;
        return;
    }

    // WT0: 2048 x 1024, tiles: nt = u>>4 (32), kt = u&15 (16)
    const int u = bid - 128;
    wt_tile(W0r, W0i, 512, 1024, 1024, u >> 4, u & 15, WT0, f32, smem);
}

// ---------------------------------------------------------------------------
// Double-buffered GEMM core: C = tanh(A @ Bt^T + bias). MT x NT tile, BK=64,
// 4 waves (2x2), 16x16x32 bf16 MFMA, XOR-swizzled LDS (slot = q ^ (row&7);
// 0 conflicts, R3). Dbuf: stage(kt+1 -> other half) | compute(kt) | barrier.
// R12: MT=NT=128 for the big GEMMs — LDS-read:MFMA ratio 0.5 (vs 0.75 at
// 64x128): per block-iter LDS 768 cyc vs MFMA 620 cyc, lifting the
// LDS-pipe-imposed MfmaUtil ceiling from ~40% to ~80%.
// XCD map partitions M (R11: FETCH 135->49 MB): xcd=bid&7 owns MS m-tiles,
// n fastest. Grid = 8*MS*GX. MODE 1: scatter r=t*64+b -> out[b][t][c].
// ---------------------------------------------------------------------------
template<int MT, int NT, int GX, int MS, int MODE>
__device__ __forceinline__ void gemm_core(int bid,
                                          const __hip_bfloat16* __restrict__ A,
                                          const __hip_bfloat16* __restrict__ Bt,
                                          const float* __restrict__ bias,
                                          void* __restrict__ Cv, int f32,
                                          int N, int K, char* smem)
{
    constexpr int AI = MT / 32;
    constexpr int BJ = NT / 32;
    constexpr int HALF = (MT + NT) * 128;

    const int tid = threadIdx.x, lane = tid & 63, w = tid >> 6;
    const int wx = w & 1, wy = w >> 1;

    const int xcd = bid & 7, r = bid >> 3;
    const int mt = xcd * MS + r / GX;
    const int nt = r % GX;
    const int m0 = mt * MT;
    const int n0 = nt * NT;

    // staging: 16B chunk at (row, slot s) holds global k-quad q = s ^ (row&7)
    const int sl = lane & 7, lr8 = lane >> 3;
    const __hip_bfloat16* gA[AI];
    const __hip_bfloat16* gB[BJ];
#pragma unroll
    for (int p = 0; p < AI; ++p) {
        const int row = w * (MT / 4) + p * 8 + lr8;
        gA[p] = A + (size_t)(m0 + row) * K + (sl ^ (row & 7)) * 8;
    }
#pragma unroll
    for (int p = 0; p < BJ; ++p) {
        const int row = w * (NT / 4) + p * 8 + lr8;
        gB[p] = Bt + (size_t)(n0 + row) * K + (sl ^ (row & 7)) * 8;
    }
    AS3 char* lA0 = (AS3 char*)smem + w * (MT * 32);
    AS3 char* lB0 = (AS3 char*)smem + MT * 128 + w * (NT * 32);

    // fragment reads: row R, k-quad KQ = ks*4+fq, slot = KQ ^ (R&7)
    const int fr = lane & 15, fq = lane >> 4;
    const int swz = (fq ^ (fr & 7)) * 8;
    const int arow = wy * (MT / 2) + fr;
    const int brow = wx * (NT / 2) + fr;

    f32x4 acc[AI][BJ];
#pragma unroll
    for (int i = 0; i < AI; ++i)
#pragma unroll
        for (int j = 0; j < BJ; ++j)
            acc[i][j] = (f32x4){0.f, 0.f, 0.f, 0.f};

    // prologue: stage kt=0 into half 0
#pragma unroll
    for (int p = 0; p < AI; ++p) gload_lds16(gA[p], lA0 + p * 1024);
#pragma unroll
    for (int p = 0; p < BJ; ++p) gload_lds16(gB[p], lB0 + p * 1024);
    __syncthreads();

    const int NKT = K >> 6;
    for (int kt = 0; kt < NKT; ++kt) {
        const int cur = (kt & 1) ? HALF : 0;
        // prefetch kt+1 into the other half (overwrites data last read at kt-1,
        // which every wave finished before the barrier that ended iter kt-1)
        if (kt + 1 < NKT) {
            const int nxt = cur ^ HALF;
            const int kk = (kt + 1) << 6;
#pragma unroll
            for (int p = 0; p < AI; ++p) gload_lds16(gA[p] + kk, lA0 + nxt + p * 1024);
#pragma unroll
            for (int p = 0; p < BJ; ++p) gload_lds16(gB[p] + kk, lB0 + nxt + p * 1024);
        }
        const __hip_bfloat16* As = (const __hip_bfloat16*)(smem + cur);
        const __hip_bfloat16* Bs = (const __hip_bfloat16*)(smem + cur + MT * 128);
#pragma unroll
        for (int ks = 0; ks < 2; ++ks) {
            const int so = swz ^ (ks << 5);
            bf16x8 af[AI], bv[BJ];
#pragma unroll
            for (int i = 0; i < AI; ++i)
                af[i] = *(const bf16x8*)(As + (arow + i * 16) * 64 + so);
#pragma unroll
            for (int j = 0; j < BJ; ++j)
                bv[j] = *(const bf16x8*)(Bs + (brow + j * 16) * 64 + so);
#pragma unroll
            for (int i = 0; i < AI; ++i)
#pragma unroll
                for (int j = 0; j < BJ; ++j)
                    acc[i][j] = __builtin_amdgcn_mfma_f32_16x16x32_bf16(af[i], bv[j], acc[i][j], 0, 0, 0);
        }
        __syncthreads();   // drains the kt+1 prefetch AFTER the compute window
    }

    // epilogue: C/D layout col = lane&15, row = (lane>>4)*4 + reg
    const int col_l = lane & 15;
    const int rq    = lane >> 4;
    float bvv[BJ];
#pragma unroll
    for (int j = 0; j < BJ; ++j)
        bvv[j] = bias[n0 + wx * (NT / 2) + j * 16 + col_l];

#pragma unroll
    for (int i = 0; i < AI; ++i) {
#pragma unroll
        for (int j = 0; j < BJ; ++j) {
            const int gc = n0 + wx * (NT / 2) + j * 16 + col_l;
#pragma unroll
            for (int r2 = 0; r2 < 4; ++r2) {
                const int gr = m0 + wy * (MT / 2) + i * 16 + rq * 4 + r2;
                const float v = fast_tanh(acc[i][j][r2] + bvv[j]);
                if (MODE == 0) {
                    ((__hip_bfloat16*)Cv)[(size_t)gr * (size_t)N + gc] = __float2bfloat16(v);
                } else {
                    const size_t idx = (size_t)(gr & 63) * 32768 + (size_t)(gr >> 6) * 256 + (size_t)gc;
                    if (f32) ((float*)Cv)[idx] = v;
                    else     ((__hip_bfloat16*)Cv)[idx] = __float2bfloat16(v);
                }
            }
        }
    }
}

// ---------------------------------------------------------------------------
// D2: blocks [0,1024) = G0 tiles (128x128 dbuf, M-partitioned XCD map:
// MS=8, GX=16); [1024,1536) = WT1 transpose; [1536,1600) = WT2 (tail slack).
// ---------------------------------------------------------------------------
__global__ __launch_bounds__(256)
void gemm0_wt(const __hip_bfloat16* __restrict__ A,
              const __hip_bfloat16* __restrict__ Bt,
              const float* __restrict__ bias, void* __restrict__ Cv,
              const void* __restrict__ W1r, const void* __restrict__ W1i,
              const void* __restrict__ W2r, const void* __restrict__ W2i,
              __hip_bfloat16* __restrict__ WT1, __hip_bfloat16* __restrict__ WT2,
              const int* __restrict__ flag)
{
    __shared__ __align__(16) char smem[65536];   // 2 x (128+128)*128
    const int bid = blockIdx.x;
    if (bid < 1024) {
        // G0: 64 m-tiles (MS=8/XCD), 16 n-tiles
        gemm_core<128, 128, 16, 8, 0>(bid, A, Bt, bias, Cv, 0, 2048, 1024, smem);
    } else if (bid < 1536) {
        const int u = bid - 1024;   // WT1: 1024 x 2048, nt = u>>5 (16), kt = u&31 (32)
        wt_tile(W1r, W1i, 1024, 512, 2048, u >> 5, u & 31, WT1, *flag, smem);
    } else {
        const int u = bid - 1536;   // WT2: 256 x 1024, nt = u>>4 (4), kt = u&15 (16)
        wt_tile(W2r, W2i, 512, 256, 1024, u >> 4, u & 15, WT2, *flag, smem);
    }
}

template<int MT, int NT, int GX, int MS, int MODE>
__global__ __launch_bounds__(256)
void gemm_k(const __hip_bfloat16* __restrict__ A, const __hip_bfloat16* __restrict__ Bt,
            const float* __restrict__ bias, void* __restrict__ Cv,
            const int* __restrict__ flag, int N, int K)
{
    __shared__ __align__(16) char smem[2 * (MT + NT) * 128];
    const int f32 = (MODE == 1) ? *flag : 0;
    gemm_core<MT, NT, GX, MS, MODE>(blockIdx.x, A, Bt, bias, Cv, f32, N, K, smem);
}

// ---------------------------------------------------------------------------
// ws: [0,16M) Z (8192x1024 bf16; reused as H1), [16M,48M) H0 (8192x2048),
// [48M) WT0 4M, [52M) WT1 4M, [56M) WT2 0.5M, [56M+512K) bias f32, [57M) flag.
// ---------------------------------------------------------------------------
extern "C" void kernel_launch(void* const* d_in, const int* in_sizes, int n_in,
                              void* d_out, int out_size, void* d_ws, size_t ws_size,
                              hipStream_t stream)
{
    (void)in_sizes; (void)n_in; (void)out_size; (void)ws_size;
    char* ws = (char*)d_ws;
    __hip_bfloat16* Z    = (__hip_bfloat16*)(ws);
    __hip_bfloat16* H0   = (__hip_bfloat16*)(ws + (16u << 20));
    __hip_bfloat16* WT0  = (__hip_bfloat16*)(ws + (48u << 20));
    __hip_bfloat16* WT1  = (__hip_bfloat16*)(ws + (52u << 20));
    __hip_bfloat16* WT2  = (__hip_bfloat16*)(ws + (56u << 20));
    float*          bias = (float*)        (ws + (56u << 20) + (512u << 10));
    int*            flag = (int*)          (ws + (57u << 20));

    // D1: hopf + WT0 + bias (+flag publish)
    setup1<<<653, 256, 0, stream>>>(d_in[0], d_in[1], d_in[2], d_in[3], d_in[4],
                                    d_in[5], d_in[6], d_in[9], d_in[10], d_in[13],
                                    Z, WT0, bias, flag, (char*)d_out);

    // D2: G0 (Z @ WT0^T -> H0, 8192x2048), 128x128 dbuf, M-partitioned XCD map
    //     + WT1/WT2 transposes in tail slack
    gemm0_wt<<<1600, 256, 0, stream>>>(Z, WT0, bias, H0,
                                       d_in[7], d_in[8], d_in[11], d_in[12],
                                       WT1, WT2, flag);

    // D3: G1 = H0 @ WT1^T -> H1=Z (8192x1024). 128x128 dbuf, 512 blocks (MS=8, GX=8).
    gemm_k<128, 128, 8, 8, 0><<<512, 256, 0, stream>>>(H0, WT1, bias + 2048, Z, flag, 1024, 2048);

    // D4: G2 = H1 @ WT2^T -> out[b][t][c] (N=256). 64x64 dbuf, 512 blocks (MS=16, GX=4).
    gemm_k<64, 64, 4, 16, 1><<<512, 256, 0, stream>>>(Z, WT2, bias + 3072, d_out, flag, 256, 1024);
}

// Round 13
// 187.650 us; speedup vs baseline: 1.1044x; 1.0235x over previous
//
#include <hip/hip_runtime.h>
#include <hip/hip_bf16.h>
#include <stdint.h>

#define AS1 __attribute__((address_space(1)))
#define AS3 __attribute__((address_space(3)))

typedef __bf16 bf16x8 __attribute__((ext_vector_type(8)));
typedef float f32x4 __attribute__((ext_vector_type(4)));

__device__ __forceinline__ float fast_tanh(float x) {
    float e = __expf(2.0f * x);           // inf/0 endpoints give +/-1 exactly, no NaN
    return 1.0f - 2.0f / (e + 1.0f);
}

__device__ __forceinline__ float ldin(const void* p, int idx, int f32) {
    return f32 ? ((const float*)p)[idx]
               : __bfloat162float(((const __hip_bfloat16*)p)[idx]);
}

__device__ __forceinline__ unsigned short f2bf(float v) {
    __hip_bfloat16 h = __float2bfloat16(v);
    return *(unsigned short*)&h;
}

// NOTE (R9 lesson): the `offset` immediate of this builtin is NOT a plain
// global-address offset on gfx950 — nonzero values corrupt the transfer.
// Always pass 0 and advance the pointer.
__device__ __forceinline__ void gload_lds16(const __hip_bfloat16* g, AS3 char* l) {
    __builtin_amdgcn_global_load_lds((AS1 void*)g, (AS3 void*)l, 16, 0, 0);
}

// ---------------------------------------------------------------------------
// 64x64 weight-transpose tile (coalesced both sides via LDS, +1-pad fp32).
// WcT[n][k] = n<dout ? [Wr | -Wi] : [Wi | Wr]  (cols: k<din | k>=din).
// smem must hold 64*65*4 = 16640 B.
// ---------------------------------------------------------------------------
__device__ __forceinline__ void wt_tile(const void* Wr, const void* Wi,
                                        int din, int dout_, int KT, int nt, int kt,
                                        __hip_bfloat16* dst, int f32, char* smem)
{
    float (*T)[65] = (float(*)[65])smem;
    const int t = threadIdx.x;
    const int n0 = nt * 64, k0 = kt * 64;
    const void* src; float sg; int col0, krel;
    if (n0 < dout_) {
        col0 = n0;
        if (k0 < din) { src = Wr; sg =  1.f; krel = k0; }
        else          { src = Wi; sg = -1.f; krel = k0 - din; }
    } else {
        col0 = n0 - dout_;
        if (k0 < din) { src = Wi; sg =  1.f; krel = k0; }
        else          { src = Wr; sg =  1.f; krel = k0 - din; }
    }
    const int lr = t >> 4, lc = t & 15;
#pragma unroll
    for (int p = 0; p < 4; ++p) {
        const int r = p * 16 + lr;
        const int c = lc * 4;
        const size_t gi = (size_t)(krel + r) * dout_ + col0 + c;
        float v0, v1, v2, v3;
        if (f32) {
            float4 v = *(const float4*)((const float*)src + gi);
            v0 = v.x; v1 = v.y; v2 = v.z; v3 = v.w;
        } else {
            ushort4 u = *(const ushort4*)((const unsigned short*)src + gi);
            __hip_bfloat16 h0, h1, h2, h3;
            *(unsigned short*)&h0 = u.x; *(unsigned short*)&h1 = u.y;
            *(unsigned short*)&h2 = u.z; *(unsigned short*)&h3 = u.w;
            v0 = __bfloat162float(h0); v1 = __bfloat162float(h1);
            v2 = __bfloat162float(h2); v3 = __bfloat162float(h3);
        }
        T[r][c] = sg * v0; T[r][c + 1] = sg * v1;
        T[r][c + 2] = sg * v2; T[r][c + 3] = sg * v3;
    }
    __syncthreads();
#pragma unroll
    for (int q = 0; q < 4; ++q) {
        const int n = q * 16 + lr;
        const int k8 = lc;
        ushort4 u;
        u.x = f2bf(T[k8 * 4 + 0][n]); u.y = f2bf(T[k8 * 4 + 1][n]);
        u.z = f2bf(T[k8 * 4 + 2][n]); u.w = f2bf(T[k8 * 4 + 3][n]);
        *(ushort4*)((unsigned short*)dst + (size_t)(n0 + n) * KT + k0 + k8 * 4) = u;
    }
}

// ---------------------------------------------------------------------------
// Setup1: 1229 blocks. [0,128) hopf | [128,640) WT0 | [640,1152) WT1 |
// [1152,1216) WT2 | [1216,1229) bias (block 1216 publishes dtype flag).
// All weight transposes here: D1 has idle CU capacity (hopf fills half the
// GPU); keeps D2 a pure single-round GEMM. Per-block inline dtype probe.
// ---------------------------------------------------------------------------
__global__ __launch_bounds__(256)
void setup1(const void* __restrict__ z, const void* __restrict__ omega,
            const void* __restrict__ bc,
            const void* __restrict__ W0r, const void* __restrict__ W0i,
            const void* __restrict__ W1r, const void* __restrict__ W1i,
            const void* __restrict__ W2r, const void* __restrict__ W2i,
            const void* __restrict__ b0r, const void* __restrict__ b0i,
            const void* __restrict__ b1r, const void* __restrict__ b1i,
            const void* __restrict__ b2r,
            __hip_bfloat16* __restrict__ Z, __hip_bfloat16* __restrict__ WT0,
            __hip_bfloat16* __restrict__ WT1, __hip_bfloat16* __restrict__ WT2,
            float* __restrict__ biasOut, int* __restrict__ flagOut,
            char* __restrict__ dout)
{
    __shared__ __align__(16) char smem[16640];
    __shared__ int sflag;
    const int t   = threadIdx.x;
    const int bid = blockIdx.x;

    if (t == 0) sflag = 0;
    __syncthreads();
    {
        const unsigned short* zz = (const unsigned short*)z;
        const int c = ((((zz[t] >> 7) & 0xFF) >= 0xC8) ? 1 : 0)
                    + ((((zz[t + 256] >> 7) & 0xFF) >= 0xC8) ? 1 : 0);
        if (c) atomicAdd(&sflag, c);
    }
    __syncthreads();
    const int f32 = (sflag > 8) ? 1 : 0;

    if (bid < 128) {
        // Hopf trajectory: one thread per (b,i), 128 fp32 Euler steps
        const int tid = bid * 256 + t;
        const int b = tid >> 9;
        const int i = tid & 511;
        float x = ldin(z, b * 1024 + i, f32);
        float y = ldin(z, b * 1024 + 512 + i, f32);
        const float om = ldin(omega, b, f32);
        const float bb = ldin(bc, b * 512 + i, f32);
        const float w  = om * (float)(i + 1);
        __hip_bfloat16* zt = Z + b * 1024 + i;
        for (int s = 0; s < 128; ++s) {
            const float r2 = x * x + y * y;
            const float f  = bb - r2;
            const float dx = f * x - w * y;
            const float dy = f * y + w * x;
            x += 0.001f * dx;
            y += 0.001f * dy;
            zt[s * 65536]       = __float2bfloat16(x);
            zt[s * 65536 + 512] = __float2bfloat16(y);
            if (s == 0) {
                if (f32) {
                    float* o = (float*)(dout + (size_t)2097152 * 4);
                    o[b * 1024 + i] = x; o[b * 1024 + 512 + i] = y;
                } else {
                    __hip_bfloat16* o = (__hip_bfloat16*)(dout + (size_t)2097152 * 2);
                    o[b * 1024 + i] = __float2bfloat16(x);
                    o[b * 1024 + 512 + i] = __float2bfloat16(y);
                }
            }
        }
        return;
    }

    if (bid >= 1216) {
        if (bid == 1216 && t == 0) *flagOut = f32;
        const int idx = (bid - 1216) * 256 + t;   // [0,3328)
        float v;
        if      (idx < 1024) v = ldin(b0r, idx, f32);
        else if (idx < 2048) v = ldin(b0i, idx - 1024, f32);
        else if (idx < 2560) v = ldin(b1r, idx - 2048, f32);
        else if (idx < 3072) v = ldin(b1i, idx - 2560, f32);
        else                 v = ldin(b2r, idx - 3072, f32);
        biasOut[idx] = v;
        return;
    }

    if (bid < 640) {
        // WT0: 2048 x 1024, nt = u>>4 (32), kt = u&15 (16)
        const int u = bid - 128;
        wt_tile(W0r, W0i, 512, 1024, 1024, u >> 4, u & 15, WT0, f32, smem);
    } else if (bid < 1152) {
        // WT1: 1024 x 2048, nt = u>>5 (16), kt = u&31 (32)
        const int u = bid - 640;
        wt_tile(W1r, W1i, 1024, 512, 2048, u >> 5, u & 31, WT1, f32, smem);
    } else {
        // WT2: 256 x 1024, nt = u>>4 (4), kt = u&15 (16)
        const int u = bid - 1152;
        wt_tile(W2r, W2i, 512, 256, 1024, u >> 4, u & 15, WT2, f32, smem);
    }
}

// ---------------------------------------------------------------------------
// Double-buffered GEMM core: C = tanh(A @ Bt^T + bias). MT x NT tile, BK=64,
// 4 waves (2x2), 16x16x32 bf16 MFMA, XOR-swizzled LDS (slot = q ^ (row&7);
// 0 conflicts, R3). Dbuf: stage(kt+1 -> other half) | compute(kt) | barrier.
// XCD map partitions M (R11: FETCH 135->49 MB): xcd=bid&7 owns MS m-tiles.
// NP (R13): each block computes NP consecutive n-tiles with the SAME A-rows —
// the 2nd tile's K-loop runs A L2-hot (halves HBM-cold iterations) and the
// grid fits one occupancy round. Grid = 8*MS*GXP, nt = (r%GXP)*NP + np.
// MODE 1: scatter r=t*64+b -> out[b][t][c], dtype per f32.
// ---------------------------------------------------------------------------
template<int MT, int NT, int GXP, int MS, int NP, int MODE>
__device__ __forceinline__ void gemm_core(int bid,
                                          const __hip_bfloat16* __restrict__ A,
                                          const __hip_bfloat16* __restrict__ Bt,
                                          const float* __restrict__ bias,
                                          void* __restrict__ Cv, int f32,
                                          int N, int K, char* smem)
{
    constexpr int AI = MT / 32;
    constexpr int BJ = NT / 32;
    constexpr int HALF = (MT + NT) * 128;

    const int tid = threadIdx.x, lane = tid & 63, w = tid >> 6;
    const int wx = w & 1, wy = w >> 1;

    const int xcd = bid & 7, r = bid >> 3;
    const int mt  = xcd * MS + r / GXP;
    const int ntp = r % GXP;
    const int m0  = mt * MT;

    // staging geometry: 16B chunk at (row, slot s) holds global k-quad q = s ^ (row&7)
    const int sl = lane & 7, lr8 = lane >> 3;
    const __hip_bfloat16* gA[AI];
#pragma unroll
    for (int p = 0; p < AI; ++p) {
        const int row = w * (MT / 4) + p * 8 + lr8;
        gA[p] = A + (size_t)(m0 + row) * K + (sl ^ (row & 7)) * 8;
    }
    AS3 char* lA0 = (AS3 char*)smem + w * (MT * 32);
    AS3 char* lB0 = (AS3 char*)smem + MT * 128 + w * (NT * 32);

    // fragment reads: row R, k-quad KQ = ks*4+fq, slot = KQ ^ (R&7)
    const int fr = lane & 15, fq = lane >> 4;
    const int swz = (fq ^ (fr & 7)) * 8;
    const int arow = wy * (MT / 2) + fr;
    const int brow = wx * (NT / 2) + fr;
    const int col_l = lane & 15;
    const int rq    = lane >> 4;

#pragma unroll 1
    for (int np = 0; np < NP; ++np) {
        const int n0 = (ntp * NP + np) * NT;

        const __hip_bfloat16* gB[BJ];
#pragma unroll
        for (int p = 0; p < BJ; ++p) {
            const int row = w * (NT / 4) + p * 8 + lr8;
            gB[p] = Bt + (size_t)(n0 + row) * K + (sl ^ (row & 7)) * 8;
        }

        f32x4 acc[AI][BJ];
#pragma unroll
        for (int i = 0; i < AI; ++i)
#pragma unroll
            for (int j = 0; j < BJ; ++j)
                acc[i][j] = (f32x4){0.f, 0.f, 0.f, 0.f};

        // prologue: stage kt=0 into half 0 (half 0 safe: all waves barriered
        // after their last reads of it in the previous np iteration)
#pragma unroll
        for (int p = 0; p < AI; ++p) gload_lds16(gA[p], lA0 + p * 1024);
#pragma unroll
        for (int p = 0; p < BJ; ++p) gload_lds16(gB[p], lB0 + p * 1024);
        __syncthreads();

        const int NKT = K >> 6;
        for (int kt = 0; kt < NKT; ++kt) {
            const int cur = (kt & 1) ? HALF : 0;
            if (kt + 1 < NKT) {
                const int nxt = cur ^ HALF;
                const int kk = (kt + 1) << 6;
#pragma unroll
                for (int p = 0; p < AI; ++p) gload_lds16(gA[p] + kk, lA0 + nxt + p * 1024);
#pragma unroll
                for (int p = 0; p < BJ; ++p) gload_lds16(gB[p] + kk, lB0 + nxt + p * 1024);
            }
            const __hip_bfloat16* As = (const __hip_bfloat16*)(smem + cur);
            const __hip_bfloat16* Bs = (const __hip_bfloat16*)(smem + cur + MT * 128);
#pragma unroll
            for (int ks = 0; ks < 2; ++ks) {
                const int so = swz ^ (ks << 5);
                bf16x8 af[AI], bv[BJ];
#pragma unroll
                for (int i = 0; i < AI; ++i)
                    af[i] = *(const bf16x8*)(As + (arow + i * 16) * 64 + so);
#pragma unroll
                for (int j = 0; j < BJ; ++j)
                    bv[j] = *(const bf16x8*)(Bs + (brow + j * 16) * 64 + so);
#pragma unroll
                for (int i = 0; i < AI; ++i)
#pragma unroll
                    for (int j = 0; j < BJ; ++j)
                        acc[i][j] = __builtin_amdgcn_mfma_f32_16x16x32_bf16(af[i], bv[j], acc[i][j], 0, 0, 0);
            }
            __syncthreads();   // drains the kt+1 prefetch AFTER the compute window
        }

        // epilogue: C/D layout col = lane&15, row = (lane>>4)*4 + reg
        float bvv[BJ];
#pragma unroll
        for (int j = 0; j < BJ; ++j)
            bvv[j] = bias[n0 + wx * (NT / 2) + j * 16 + col_l];

#pragma unroll
        for (int i = 0; i < AI; ++i) {
#pragma unroll
            for (int j = 0; j < BJ; ++j) {
                const int gc = n0 + wx * (NT / 2) + j * 16 + col_l;
#pragma unroll
                for (int r2 = 0; r2 < 4; ++r2) {
                    const int gr = m0 + wy * (MT / 2) + i * 16 + rq * 4 + r2;
                    const float v = fast_tanh(acc[i][j][r2] + bvv[j]);
                    if (MODE == 0) {
                        ((__hip_bfloat16*)Cv)[(size_t)gr * (size_t)N + gc] = __float2bfloat16(v);
                    } else {
                        const size_t idx = (size_t)(gr & 63) * 32768 + (size_t)(gr >> 6) * 256 + (size_t)gc;
                        if (f32) ((float*)Cv)[idx] = v;
                        else     ((__hip_bfloat16*)Cv)[idx] = __float2bfloat16(v);
                    }
                }
            }
        }
    }
}

template<int MT, int NT, int GXP, int MS, int NP, int MODE>
__global__ __launch_bounds__(256)
void gemm_k(const __hip_bfloat16* __restrict__ A, const __hip_bfloat16* __restrict__ Bt,
            const float* __restrict__ bias, void* __restrict__ Cv,
            const int* __restrict__ flag, int N, int K)
{
    __shared__ __align__(16) char smem[2 * (MT + NT) * 128];
    const int f32 = (MODE == 1) ? *flag : 0;
    gemm_core<MT, NT, GXP, MS, NP, MODE>(blockIdx.x, A, Bt, bias, Cv, f32, N, K, smem);
}

// ---------------------------------------------------------------------------
// ws: [0,16M) Z (8192x1024 bf16; reused as H1), [16M,48M) H0 (8192x2048),
// [48M) WT0 4M, [52M) WT1 4M, [56M) WT2 0.5M, [56M+512K) bias f32, [57M) flag.
// ---------------------------------------------------------------------------
extern "C" void kernel_launch(void* const* d_in, const int* in_sizes, int n_in,
                              void* d_out, int out_size, void* d_ws, size_t ws_size,
                              hipStream_t stream)
{
    (void)in_sizes; (void)n_in; (void)out_size; (void)ws_size;
    char* ws = (char*)d_ws;
    __hip_bfloat16* Z    = (__hip_bfloat16*)(ws);
    __hip_bfloat16* H0   = (__hip_bfloat16*)(ws + (16u << 20));
    __hip_bfloat16* WT0  = (__hip_bfloat16*)(ws + (48u << 20));
    __hip_bfloat16* WT1  = (__hip_bfloat16*)(ws + (52u << 20));
    __hip_bfloat16* WT2  = (__hip_bfloat16*)(ws + (56u << 20));
    float*          bias = (float*)        (ws + (56u << 20) + (512u << 10));
    int*            flag = (int*)          (ws + (57u << 20));

    // D1: hopf + ALL weight transposes + bias (+flag publish)
    setup1<<<1229, 256, 0, stream>>>(d_in[0], d_in[1], d_in[2],
                                     d_in[3], d_in[4], d_in[7], d_in[8], d_in[11], d_in[12],
                                     d_in[5], d_in[6], d_in[9], d_in[10], d_in[13],
                                     Z, WT0, WT1, WT2, bias, flag, (char*)d_out);

    // D2: G0 = Z @ WT0^T -> H0 (8192x2048). 128x128 dbuf, n-pairs: 512 blocks
    //     (MS=8, GXP=8, NP=2) — one occupancy round, A L2-hot on 2nd tile.
    gemm_k<128, 128, 8, 8, 2, 0><<<512, 256, 0, stream>>>(Z, WT0, bias, H0, flag, 2048, 1024);

    // D3: G1 = H0 @ WT1^T -> H1=Z (8192x1024). 128x128 dbuf, 512 blocks (MS=8, GXP=8, NP=1).
    gemm_k<128, 128, 8, 8, 1, 0><<<512, 256, 0, stream>>>(H0, WT1, bias + 2048, Z, flag, 1024, 2048);

    // D4: G2 = H1 @ WT2^T -> out[b][t][c] (N=256). 64x64 dbuf, 512 blocks (MS=16, GXP=4, NP=1).
    gemm_k<64, 64, 4, 16, 1, 1><<<512, 256, 0, stream>>>(Z, WT2, bias + 3072, d_out, flag, 256, 1024);
}